// Round 6
// baseline (619.863 us; speedup 1.0000x reference)
//
#include <hip/hip_runtime.h>

#define NUM_USERS 80000
#define NUM_ITEMS 40000
#define NUM_NODES 120000
#define DIM 64
#define ALPHA_C 0.8f

typedef unsigned short u16;
typedef unsigned int u32;

// fp32 -> bf16 round-nearest-even
__device__ __forceinline__ u16 f2bf(float f) {
    union { float f; u32 i; } v;
    v.f = f;
    u32 i = v.i;
    u32 r = (i + 0x7FFFu + ((i >> 16) & 1u)) >> 16;
    return (u16)r;
}
__device__ __forceinline__ float lo_bf(u32 u) { return __uint_as_float(u << 16); }
__device__ __forceinline__ float hi_bf(u32 u) { return __uint_as_float(u & 0xffff0000u); }

// accumulate 8 bf16 (packed in uint4) * v into acc[8]
__device__ __forceinline__ void acc8(float* __restrict__ acc, float v, uint4 q) {
    const u32* p = (const u32*)&q;
#pragma unroll
    for (int k = 0; k < 4; ++k) {
        u32 u = p[k];
        acc[2 * k]     = fmaf(v, lo_bf(u), acc[2 * k]);
        acc[2 * k + 1] = fmaf(v, hi_bf(u), acc[2 * k + 1]);
    }
}

__device__ __forceinline__ uint4 ldrow(const u16* __restrict__ x, int c, int li) {
    return *((const uint4*)(x + (size_t)c * DIM) + li);
}

// ---------------------------------------------------------------------------
// Software-pipelined segment gather (8-lane group walks its whole segment).
// 2-stage prefetch of col/val + 1-stage prefetch of row gathers.
// Lane li (0..7) owns elements [8*li, 8*li+8) of the 64-dim row.
// ---------------------------------------------------------------------------
__device__ __forceinline__ void seg_pipe(const int* __restrict__ col,
                                         const float* __restrict__ val,
                                         int start, int end,
                                         const u16* __restrict__ x,
                                         int li, float* __restrict__ acc) {
    int n = end - start;
    const int* cp = col + start;
    const float* vp = val + start;
    int np = n >> 1;
    if (np >= 2) {
        int   ca0 = cp[0], ca1 = cp[1];
        float va0 = vp[0], va1 = vp[1];
        int   cb0 = cp[2], cb1 = cp[3];
        float vb0 = vp[2], vb1 = vp[3];
        uint4 xa0 = ldrow(x, ca0, li);
        uint4 xa1 = ldrow(x, ca1, li);
        for (int p = 2; p < np; ++p) {
            int   cc0 = cp[2 * p],     cc1 = cp[2 * p + 1];
            float vc0 = vp[2 * p],     vc1 = vp[2 * p + 1];
            uint4 xb0 = ldrow(x, cb0, li);
            uint4 xb1 = ldrow(x, cb1, li);
            acc8(acc, va0, xa0);
            acc8(acc, va1, xa1);
            va0 = vb0; va1 = vb1; xa0 = xb0; xa1 = xb1;
            cb0 = cc0; cb1 = cc1; vb0 = vc0; vb1 = vc1;
        }
        uint4 xb0 = ldrow(x, cb0, li);
        uint4 xb1 = ldrow(x, cb1, li);
        acc8(acc, va0, xa0);
        acc8(acc, va1, xa1);
        acc8(acc, vb0, xb0);
        acc8(acc, vb1, xb1);
        if (n & 1) {
            int c = cp[n - 1];
            float v = vp[n - 1];
            uint4 xq = ldrow(x, c, li);
            acc8(acc, v, xq);
        }
    } else {
        for (int e = 0; e < n; ++e) {
            int c = cp[e];
            float v = vp[e];
            uint4 xq = ldrow(x, c, li);
            acc8(acc, v, xq);
        }
    }
}

// ---------------------------------------------------------------------------
// K1: softmax over theta (6 elements) -> theta_w
// ---------------------------------------------------------------------------
__global__ void k_softmax_theta(const float* __restrict__ theta,
                                float* __restrict__ theta_w) {
    if (threadIdx.x == 0 && blockIdx.x == 0) {
        float m = -1e30f;
        for (int i = 0; i < 6; ++i) m = fmaxf(m, theta[i]);
        float e[6];
        float s = 0.f;
        for (int i = 0; i < 6; ++i) { e[i] = expf(theta[i] - m); s += e[i]; }
        for (int i = 0; i < 6; ++i) theta_w[i] = e[i] / s;
    }
}

// ---------------------------------------------------------------------------
// K2: exp_v[e] = exp(dot(p_counts[e,0:6], theta_w)); row_sum[r] += exp_v[e]
// ---------------------------------------------------------------------------
__global__ void k_expv(const float* __restrict__ p_counts,
                       const float* __restrict__ theta_w,
                       const int* __restrict__ p_row,
                       float* __restrict__ exp_v,
                       float* __restrict__ row_sum, int E) {
    int i = blockIdx.x * blockDim.x + threadIdx.x;
    if (i >= E) return;
    const float* c = p_counts + (size_t)i * 6;
    float v = c[0] * theta_w[0] + c[1] * theta_w[1] + c[2] * theta_w[2] +
              c[3] * theta_w[3] + c[4] * theta_w[4] + c[5] * theta_w[5];
    float ev = expf(v);
    exp_v[i] = ev;
    atomicAdd(&row_sum[p_row[i]], ev);
}

// ---------------------------------------------------------------------------
// K3: all three CSR row_ptr arrays in one launch (rows sorted: np.unique)
// ---------------------------------------------------------------------------
__device__ __forceinline__ void lower_bound_ptr(const int* __restrict__ rows,
                                                int nnz, int r,
                                                int* __restrict__ ptr) {
    int lo = 0, hi = nnz;
    while (lo < hi) {
        int mid = (lo + hi) >> 1;
        if (rows[mid] < r) lo = mid + 1; else hi = mid;
    }
    ptr[r] = lo;
}

__global__ void k_row_ptr3(const int* __restrict__ rows_a, int nnz_a, int* __restrict__ pa,
                           const int* __restrict__ rows_b, int nnz_b, int* __restrict__ pb,
                           const int* __restrict__ rows_c, int nnz_c, int* __restrict__ pc) {
    int t = blockIdx.x * blockDim.x + threadIdx.x;
    int which = t / (NUM_NODES + 1);
    int r = t - which * (NUM_NODES + 1);
    if (which == 0) lower_bound_ptr(rows_a, nnz_a, r, pa);
    else if (which == 1) lower_bound_ptr(rows_b, nnz_b, r, pb);
    else if (which == 2) lower_bound_ptr(rows_c, nnz_c, r, pc);
}

// ---------------------------------------------------------------------------
// K4: convert user_emb || item_emb (fp32) -> bf16 table
// ---------------------------------------------------------------------------
__global__ void k_cvt(const float* __restrict__ user_emb,
                      const float* __restrict__ item_emb,
                      u16* __restrict__ emb16) {
    int i = blockIdx.x * blockDim.x + threadIdx.x;   // handles 4 floats
    size_t f = (size_t)i * 4;
    const size_t UTOT = (size_t)NUM_USERS * DIM;
    const size_t TOT = (size_t)NUM_NODES * DIM;
    if (f >= TOT) return;
    float4 v = (f < UTOT) ? *(const float4*)(user_emb + f)
                          : *(const float4*)(item_emb + (f - UTOT));
    ushort4 o;
    o.x = f2bf(v.x); o.y = f2bf(v.y); o.z = f2bf(v.z); o.w = f2bf(v.w);
    *(ushort4*)(emb16 + f) = o;
}

// ---------------------------------------------------------------------------
// K5: build merged pos+neg CSR: per row, pos entries (w=val) then neg
//     entries (w=-ALPHA*val). dest_pos(e)=e+rp_n[row]; dest_neg(e)=rp_p[row+1]+e.
// ---------------------------------------------------------------------------
__global__ void k_merge(const int* __restrict__ pos_row, const int* __restrict__ pos_col,
                        const float* __restrict__ pos_val, int E_pos,
                        const int* __restrict__ neg_row, const int* __restrict__ neg_col,
                        const float* __restrict__ neg_val, int E_neg,
                        const int* __restrict__ rp_p, const int* __restrict__ rp_n,
                        int* __restrict__ m_col, float* __restrict__ m_val) {
    int i = blockIdx.x * blockDim.x + threadIdx.x;
    if (i < E_pos) {
        int r = pos_row[i];
        int d = i + rp_n[r];
        m_col[d] = pos_col[i];
        m_val[d] = pos_val[i];
    } else {
        int j = i - E_pos;
        if (j >= E_neg) return;
        int r = neg_row[j];
        int d = rp_p[r + 1] + j;
        m_col[d] = neg_col[j];
        m_val[d] = -ALPHA_C * neg_val[j];
    }
}

// ---------------------------------------------------------------------------
// K6: path SpMM with fused row-softmax. One 8-lane group per row.
//     acc = sum_e exp_v[e]*x[col[e]]; result = acc * inv (weights linear)
// ---------------------------------------------------------------------------
__global__ void k_path(const u16* __restrict__ emb16,
                       const float* __restrict__ exp_v,
                       const float* __restrict__ row_sum,
                       const int* __restrict__ rp,
                       const int* __restrict__ cols,
                       u16* __restrict__ e0,
                       float* __restrict__ sum_out) {
    int t = blockIdx.x * blockDim.x + threadIdx.x;
    int row = t >> 3;            // one 8-lane group per row
    if (row >= NUM_NODES) return;
    int li = threadIdx.x & 7;
    int start = rp[row], end = rp[row + 1];
    float inv = 1.0f / (row_sum[row] + 1e-12f);

    float acc[8];
#pragma unroll
    for (int k = 0; k < 8; ++k) acc[k] = 0.f;

    seg_pipe(cols, exp_v, start, end, emb16, li, acc);

#pragma unroll
    for (int k = 0; k < 8; ++k) acc[k] *= inv;

    u32 o[4];
#pragma unroll
    for (int k = 0; k < 4; ++k)
        o[k] = (u32)f2bf(acc[2 * k]) | ((u32)f2bf(acc[2 * k + 1]) << 16);
    *((uint4*)(e0 + (size_t)row * DIM) + li) = *(uint4*)o;
    float4* sp = (float4*)(sum_out + (size_t)row * DIM) + li * 2;
    sp[0] = make_float4(acc[0], acc[1], acc[2], acc[3]);
    sp[1] = make_float4(acc[4], acc[5], acc[6], acc[7]);
}

// ---------------------------------------------------------------------------
// K7: one propagation layer over the MERGED CSR. One 8-lane group per row.
//     res = mergedAcc + ALPHA * e_in[row]
//     sum_io += res ; final layer: sum_io = (sum_io + res) * 0.25
// ---------------------------------------------------------------------------
__global__ void k_layer(const u16* __restrict__ e_in,
                        u16* __restrict__ e_out,
                        float* __restrict__ sum_io,
                        const int* __restrict__ rp_p,
                        const int* __restrict__ rp_n,
                        const int* __restrict__ m_col,
                        const float* __restrict__ m_val,
                        int is_final) {
    int t = blockIdx.x * blockDim.x + threadIdx.x;
    int row = t >> 3;            // one 8-lane group per row
    if (row >= NUM_NODES) return;
    int li = threadIdx.x & 7;
    int start = rp_p[row] + rp_n[row];
    int end   = rp_p[row + 1] + rp_n[row + 1];

    uint4 eq = *((const uint4*)(e_in + (size_t)row * DIM) + li);  // overlap with walk

    float acc[8];
#pragma unroll
    for (int k = 0; k < 8; ++k) acc[k] = 0.f;

    seg_pipe(m_col, m_val, start, end, e_in, li, acc);

    const u32* ep = (const u32*)&eq;
    float res[8];
#pragma unroll
    for (int k = 0; k < 4; ++k) {
        res[2 * k]     = acc[2 * k]     + ALPHA_C * lo_bf(ep[k]);
        res[2 * k + 1] = acc[2 * k + 1] + ALPHA_C * hi_bf(ep[k]);
    }
    float4* sp = (float4*)(sum_io + (size_t)row * DIM) + li * 2;
    float4 s0 = sp[0], s1 = sp[1];
    s0.x += res[0]; s0.y += res[1]; s0.z += res[2]; s0.w += res[3];
    s1.x += res[4]; s1.y += res[5]; s1.z += res[6]; s1.w += res[7];
    if (is_final) {
        s0.x *= 0.25f; s0.y *= 0.25f; s0.z *= 0.25f; s0.w *= 0.25f;
        s1.x *= 0.25f; s1.y *= 0.25f; s1.z *= 0.25f; s1.w *= 0.25f;
    }
    sp[0] = s0; sp[1] = s1;
    if (!is_final) {
        u32 o[4];
#pragma unroll
        for (int k = 0; k < 4; ++k)
            o[k] = (u32)f2bf(res[2 * k]) | ((u32)f2bf(res[2 * k + 1]) << 16);
        *((uint4*)(e_out + (size_t)row * DIM) + li) = *(uint4*)o;
    }
}

// ---------------------------------------------------------------------------
extern "C" void kernel_launch(void* const* d_in, const int* in_sizes, int n_in,
                              void* d_out, int out_size, void* d_ws, size_t ws_size,
                              hipStream_t stream) {
    const float* user_emb = (const float*)d_in[0];
    const float* item_emb = (const float*)d_in[1];
    const float* theta    = (const float*)d_in[2];
    const int*   pos_row  = (const int*)d_in[3];
    const int*   pos_col  = (const int*)d_in[4];
    const float* pos_val  = (const float*)d_in[5];
    const int*   neg_row  = (const int*)d_in[6];
    const int*   neg_col  = (const int*)d_in[7];
    const float* neg_val  = (const float*)d_in[8];
    const int*   p_row    = (const int*)d_in[9];
    const int*   p_col    = (const int*)d_in[10];
    const float* p_counts = (const float*)d_in[11];
    const int E_pos  = in_sizes[3];
    const int E_neg  = in_sizes[6];
    const int E_path = in_sizes[9];

    // bump allocator over d_ws (256B aligned chunks)
    char* wsb = (char*)d_ws;
    size_t off = 0;
    auto alloc = [&](size_t bytes) -> void* {
        void* p = wsb + off;
        off = (off + bytes + 255) & ~(size_t)255;
        return p;
    };
    float* theta_w = (float*)alloc(6 * sizeof(float));
    float* exp_v   = (float*)alloc((size_t)E_path * sizeof(float));
    float* row_sum = (float*)alloc((size_t)NUM_NODES * sizeof(float));
    int*   rp_pos  = (int*)alloc((size_t)(NUM_NODES + 1) * sizeof(int));
    int*   rp_neg  = (int*)alloc((size_t)(NUM_NODES + 1) * sizeof(int));
    int*   rp_path = (int*)alloc((size_t)(NUM_NODES + 1) * sizeof(int));
    u16*   emb16   = (u16*)alloc((size_t)NUM_NODES * DIM * sizeof(u16));
    u16*   eA      = (u16*)alloc((size_t)NUM_NODES * DIM * sizeof(u16));
    u16*   eB      = (u16*)alloc((size_t)NUM_NODES * DIM * sizeof(u16));
    int*   m_col   = (int*)alloc((size_t)(E_pos + E_neg) * sizeof(int));
    float* m_val   = (float*)alloc((size_t)(E_pos + E_neg) * sizeof(float));
    float* sum_io  = (float*)d_out;  // running sum accumulates directly in d_out

    hipMemsetAsync(row_sum, 0, (size_t)NUM_NODES * sizeof(float), stream);

    k_softmax_theta<<<1, 64, 0, stream>>>(theta, theta_w);
    k_expv<<<(E_path + 255) / 256, 256, 0, stream>>>(p_counts, theta_w, p_row,
                                                     exp_v, row_sum, E_path);

    int total_rp = 3 * (NUM_NODES + 1);
    k_row_ptr3<<<(total_rp + 255) / 256, 256, 0, stream>>>(
        pos_row, E_pos, rp_pos, neg_row, E_neg, rp_neg, p_row, E_path, rp_path);

    int cvt_threads = (NUM_NODES * DIM) / 4;
    k_cvt<<<(cvt_threads + 255) / 256, 256, 0, stream>>>(user_emb, item_emb, emb16);

    int merge_threads = E_pos + E_neg;
    k_merge<<<(merge_threads + 255) / 256, 256, 0, stream>>>(
        pos_row, pos_col, pos_val, E_pos,
        neg_row, neg_col, neg_val, E_neg,
        rp_pos, rp_neg, m_col, m_val);

    // one 8-lane group per row: 32 rows per 256-thread block
    int row_blocks = (NUM_NODES + 31) / 32;  // 3750

    k_path<<<row_blocks, 256, 0, stream>>>(emb16, exp_v, row_sum, rp_path,
                                           p_col, eA, sum_io);
    k_layer<<<row_blocks, 256, 0, stream>>>(eA, eB, sum_io, rp_pos, rp_neg,
                                            m_col, m_val, 0);
    k_layer<<<row_blocks, 256, 0, stream>>>(eB, eA, sum_io, rp_pos, rp_neg,
                                            m_col, m_val, 0);
    k_layer<<<row_blocks, 256, 0, stream>>>(eA, eB, sum_io, rp_pos, rp_neg,
                                            m_col, m_val, 1);
}

// Round 7
// 521.026 us; speedup vs baseline: 1.1897x; 1.1897x over previous
//
#include <hip/hip_runtime.h>

#define NUM_USERS 80000
#define NUM_ITEMS 40000
#define NUM_NODES 120000
#define DIM 64
#define ALPHA_C 0.8f

typedef unsigned short u16;
typedef unsigned int u32;

// fp32 -> bf16 round-nearest-even
__device__ __forceinline__ u16 f2bf(float f) {
    union { float f; u32 i; } v;
    v.f = f;
    u32 i = v.i;
    u32 r = (i + 0x7FFFu + ((i >> 16) & 1u)) >> 16;
    return (u16)r;
}
__device__ __forceinline__ float lo_bf(u32 u) { return __uint_as_float(u << 16); }
__device__ __forceinline__ float hi_bf(u32 u) { return __uint_as_float(u & 0xffff0000u); }

// accumulate 8 bf16 (packed in uint4) * v into acc[8]
__device__ __forceinline__ void acc8(float* __restrict__ acc, float v, uint4 q) {
    const u32* p = (const u32*)&q;
#pragma unroll
    for (int k = 0; k < 4; ++k) {
        u32 u = p[k];
        acc[2 * k]     = fmaf(v, lo_bf(u), acc[2 * k]);
        acc[2 * k + 1] = fmaf(v, hi_bf(u), acc[2 * k + 1]);
    }
}

__device__ __forceinline__ uint4 ldrow(const u16* __restrict__ x, int c, int li) {
    return *((const uint4*)(x + (size_t)c * DIM) + li);
}

// ---------------------------------------------------------------------------
// Software-pipelined segment gather (8-lane group walks its whole segment).
// 2-stage prefetch of col/val + 1-stage prefetch of row gathers.
// Lane li (0..7) owns elements [8*li, 8*li+8) of the 64-dim row.
// If SUMV, also accumulates the sum of val over the segment into *vsum
// (every lane reads every val in the group-serial walk, so no reduction).
// ---------------------------------------------------------------------------
template <bool SUMV>
__device__ __forceinline__ void seg_pipe_t(const int* __restrict__ col,
                                           const float* __restrict__ val,
                                           int start, int end,
                                           const u16* __restrict__ x,
                                           int li, float* __restrict__ acc,
                                           float* __restrict__ vsum) {
    int n = end - start;
    const int* cp = col + start;
    const float* vp = val + start;
    float s = 0.f;
    int np = n >> 1;
    if (np >= 2) {
        float va0 = vp[0], va1 = vp[1];
        int   cb0 = cp[2], cb1 = cp[3];
        float vb0 = vp[2], vb1 = vp[3];
        uint4 xa0 = ldrow(x, cp[0], li);
        uint4 xa1 = ldrow(x, cp[1], li);
        for (int p = 2; p < np; ++p) {
            int   cc0 = cp[2 * p],     cc1 = cp[2 * p + 1];
            float vc0 = vp[2 * p],     vc1 = vp[2 * p + 1];
            uint4 xb0 = ldrow(x, cb0, li);
            uint4 xb1 = ldrow(x, cb1, li);
            acc8(acc, va0, xa0);
            acc8(acc, va1, xa1);
            if (SUMV) s += va0 + va1;
            va0 = vb0; va1 = vb1; xa0 = xb0; xa1 = xb1;
            cb0 = cc0; cb1 = cc1; vb0 = vc0; vb1 = vc1;
        }
        uint4 xb0 = ldrow(x, cb0, li);
        uint4 xb1 = ldrow(x, cb1, li);
        acc8(acc, va0, xa0);
        acc8(acc, va1, xa1);
        acc8(acc, vb0, xb0);
        acc8(acc, vb1, xb1);
        if (SUMV) s += va0 + va1 + vb0 + vb1;
        if (n & 1) {
            float v = vp[n - 1];
            uint4 xq = ldrow(x, cp[n - 1], li);
            acc8(acc, v, xq);
            if (SUMV) s += v;
        }
    } else {
        for (int e = 0; e < n; ++e) {
            float v = vp[e];
            uint4 xq = ldrow(x, cp[e], li);
            acc8(acc, v, xq);
            if (SUMV) s += v;
        }
    }
    if (SUMV) *vsum = s;
}

// ---------------------------------------------------------------------------
// K1: softmax over theta (6 elements) -> theta_w
// ---------------------------------------------------------------------------
__global__ void k_softmax_theta(const float* __restrict__ theta,
                                float* __restrict__ theta_w) {
    if (threadIdx.x == 0 && blockIdx.x == 0) {
        float m = -1e30f;
        for (int i = 0; i < 6; ++i) m = fmaxf(m, theta[i]);
        float e[6];
        float s = 0.f;
        for (int i = 0; i < 6; ++i) { e[i] = expf(theta[i] - m); s += e[i]; }
        for (int i = 0; i < 6; ++i) theta_w[i] = e[i] / s;
    }
}

// ---------------------------------------------------------------------------
// K2: exp_v[e] = exp(dot(p_counts[e,0:6], theta_w))   (no atomics)
// ---------------------------------------------------------------------------
__global__ void k_expv(const float* __restrict__ p_counts,
                       const float* __restrict__ theta_w,
                       float* __restrict__ exp_v, int E) {
    int i = blockIdx.x * blockDim.x + threadIdx.x;
    if (i >= E) return;
    const float* c = p_counts + (size_t)i * 6;
    float v = c[0] * theta_w[0] + c[1] * theta_w[1] + c[2] * theta_w[2] +
              c[3] * theta_w[3] + c[4] * theta_w[4] + c[5] * theta_w[5];
    exp_v[i] = expf(v);
}

// ---------------------------------------------------------------------------
// K3: all three CSR row_ptr arrays in one launch (rows sorted: np.unique)
// ---------------------------------------------------------------------------
__device__ __forceinline__ void lower_bound_ptr(const int* __restrict__ rows,
                                                int nnz, int r,
                                                int* __restrict__ ptr) {
    int lo = 0, hi = nnz;
    while (lo < hi) {
        int mid = (lo + hi) >> 1;
        if (rows[mid] < r) lo = mid + 1; else hi = mid;
    }
    ptr[r] = lo;
}

__global__ void k_row_ptr3(const int* __restrict__ rows_a, int nnz_a, int* __restrict__ pa,
                           const int* __restrict__ rows_b, int nnz_b, int* __restrict__ pb,
                           const int* __restrict__ rows_c, int nnz_c, int* __restrict__ pc) {
    int t = blockIdx.x * blockDim.x + threadIdx.x;
    int which = t / (NUM_NODES + 1);
    int r = t - which * (NUM_NODES + 1);
    if (which == 0) lower_bound_ptr(rows_a, nnz_a, r, pa);
    else if (which == 1) lower_bound_ptr(rows_b, nnz_b, r, pb);
    else if (which == 2) lower_bound_ptr(rows_c, nnz_c, r, pc);
}

// ---------------------------------------------------------------------------
// K4: convert user_emb || item_emb (fp32) -> bf16 table
// ---------------------------------------------------------------------------
__global__ void k_cvt(const float* __restrict__ user_emb,
                      const float* __restrict__ item_emb,
                      u16* __restrict__ emb16) {
    int i = blockIdx.x * blockDim.x + threadIdx.x;   // handles 4 floats
    size_t f = (size_t)i * 4;
    const size_t UTOT = (size_t)NUM_USERS * DIM;
    const size_t TOT = (size_t)NUM_NODES * DIM;
    if (f >= TOT) return;
    float4 v = (f < UTOT) ? *(const float4*)(user_emb + f)
                          : *(const float4*)(item_emb + (f - UTOT));
    ushort4 o;
    o.x = f2bf(v.x); o.y = f2bf(v.y); o.z = f2bf(v.z); o.w = f2bf(v.w);
    *(ushort4*)(emb16 + f) = o;
}

// ---------------------------------------------------------------------------
// K5: build merged pos+neg CSR: per row, pos entries (w=val) then neg
//     entries (w=-ALPHA*val). dest_pos(e)=e+rp_n[row]; dest_neg(e)=rp_p[row+1]+e.
// ---------------------------------------------------------------------------
__global__ void k_merge(const int* __restrict__ pos_row, const int* __restrict__ pos_col,
                        const float* __restrict__ pos_val, int E_pos,
                        const int* __restrict__ neg_row, const int* __restrict__ neg_col,
                        const float* __restrict__ neg_val, int E_neg,
                        const int* __restrict__ rp_p, const int* __restrict__ rp_n,
                        int* __restrict__ m_col, float* __restrict__ m_val) {
    int i = blockIdx.x * blockDim.x + threadIdx.x;
    if (i < E_pos) {
        int r = pos_row[i];
        int d = i + rp_n[r];
        m_col[d] = pos_col[i];
        m_val[d] = pos_val[i];
    } else {
        int j = i - E_pos;
        if (j >= E_neg) return;
        int r = neg_row[j];
        int d = rp_p[r + 1] + j;
        m_col[d] = neg_col[j];
        m_val[d] = -ALPHA_C * neg_val[j];
    }
}

// ---------------------------------------------------------------------------
// K6: path SpMM with fused row-softmax. One 8-lane group per row.
//     acc = sum_e exp_v[e]*x[col[e]]; denominator accumulated in-walk;
//     result = acc / (sum + 1e-12)  (weights enter linearly)
// ---------------------------------------------------------------------------
__global__ void k_path(const u16* __restrict__ emb16,
                       const float* __restrict__ exp_v,
                       const int* __restrict__ rp,
                       const int* __restrict__ cols,
                       u16* __restrict__ e0,
                       float* __restrict__ sum_out) {
    int t = blockIdx.x * blockDim.x + threadIdx.x;
    int row = t >> 3;            // one 8-lane group per row
    if (row >= NUM_NODES) return;
    int li = threadIdx.x & 7;
    int start = rp[row], end = rp[row + 1];

    float acc[8];
#pragma unroll
    for (int k = 0; k < 8; ++k) acc[k] = 0.f;
    float s = 0.f;

    seg_pipe_t<true>(cols, exp_v, start, end, emb16, li, acc, &s);

    float inv = 1.0f / (s + 1e-12f);
#pragma unroll
    for (int k = 0; k < 8; ++k) acc[k] *= inv;

    u32 o[4];
#pragma unroll
    for (int k = 0; k < 4; ++k)
        o[k] = (u32)f2bf(acc[2 * k]) | ((u32)f2bf(acc[2 * k + 1]) << 16);
    *((uint4*)(e0 + (size_t)row * DIM) + li) = *(uint4*)o;
    float4* sp = (float4*)(sum_out + (size_t)row * DIM) + li * 2;
    sp[0] = make_float4(acc[0], acc[1], acc[2], acc[3]);
    sp[1] = make_float4(acc[4], acc[5], acc[6], acc[7]);
}

// ---------------------------------------------------------------------------
// K7: one propagation layer over the MERGED CSR. One 8-lane group per row.
//     res = mergedAcc + ALPHA * e_in[row]
//     sum_io += res ; final layer: sum_io = (sum_io + res) * 0.25
// ---------------------------------------------------------------------------
__global__ void k_layer(const u16* __restrict__ e_in,
                        u16* __restrict__ e_out,
                        float* __restrict__ sum_io,
                        const int* __restrict__ rp_p,
                        const int* __restrict__ rp_n,
                        const int* __restrict__ m_col,
                        const float* __restrict__ m_val,
                        int is_final) {
    int t = blockIdx.x * blockDim.x + threadIdx.x;
    int row = t >> 3;            // one 8-lane group per row
    if (row >= NUM_NODES) return;
    int li = threadIdx.x & 7;
    int start = rp_p[row] + rp_n[row];
    int end   = rp_p[row + 1] + rp_n[row + 1];

    uint4 eq = *((const uint4*)(e_in + (size_t)row * DIM) + li);  // overlap with walk

    float acc[8];
#pragma unroll
    for (int k = 0; k < 8; ++k) acc[k] = 0.f;

    seg_pipe_t<false>(m_col, m_val, start, end, e_in, li, acc, nullptr);

    const u32* ep = (const u32*)&eq;
    float res[8];
#pragma unroll
    for (int k = 0; k < 4; ++k) {
        res[2 * k]     = acc[2 * k]     + ALPHA_C * lo_bf(ep[k]);
        res[2 * k + 1] = acc[2 * k + 1] + ALPHA_C * hi_bf(ep[k]);
    }
    float4* sp = (float4*)(sum_io + (size_t)row * DIM) + li * 2;
    float4 s0 = sp[0], s1 = sp[1];
    s0.x += res[0]; s0.y += res[1]; s0.z += res[2]; s0.w += res[3];
    s1.x += res[4]; s1.y += res[5]; s1.z += res[6]; s1.w += res[7];
    if (is_final) {
        s0.x *= 0.25f; s0.y *= 0.25f; s0.z *= 0.25f; s0.w *= 0.25f;
        s1.x *= 0.25f; s1.y *= 0.25f; s1.z *= 0.25f; s1.w *= 0.25f;
    }
    sp[0] = s0; sp[1] = s1;
    if (!is_final) {
        u32 o[4];
#pragma unroll
        for (int k = 0; k < 4; ++k)
            o[k] = (u32)f2bf(res[2 * k]) | ((u32)f2bf(res[2 * k + 1]) << 16);
        *((uint4*)(e_out + (size_t)row * DIM) + li) = *(uint4*)o;
    }
}

// ---------------------------------------------------------------------------
extern "C" void kernel_launch(void* const* d_in, const int* in_sizes, int n_in,
                              void* d_out, int out_size, void* d_ws, size_t ws_size,
                              hipStream_t stream) {
    const float* user_emb = (const float*)d_in[0];
    const float* item_emb = (const float*)d_in[1];
    const float* theta    = (const float*)d_in[2];
    const int*   pos_row  = (const int*)d_in[3];
    const int*   pos_col  = (const int*)d_in[4];
    const float* pos_val  = (const float*)d_in[5];
    const int*   neg_row  = (const int*)d_in[6];
    const int*   neg_col  = (const int*)d_in[7];
    const float* neg_val  = (const float*)d_in[8];
    const int*   p_row    = (const int*)d_in[9];
    const int*   p_col    = (const int*)d_in[10];
    const float* p_counts = (const float*)d_in[11];
    const int E_pos  = in_sizes[3];
    const int E_neg  = in_sizes[6];
    const int E_path = in_sizes[9];

    // bump allocator over d_ws (256B aligned chunks)
    char* wsb = (char*)d_ws;
    size_t off = 0;
    auto alloc = [&](size_t bytes) -> void* {
        void* p = wsb + off;
        off = (off + bytes + 255) & ~(size_t)255;
        return p;
    };
    float* theta_w = (float*)alloc(6 * sizeof(float));
    float* exp_v   = (float*)alloc((size_t)E_path * sizeof(float));
    int*   rp_pos  = (int*)alloc((size_t)(NUM_NODES + 1) * sizeof(int));
    int*   rp_neg  = (int*)alloc((size_t)(NUM_NODES + 1) * sizeof(int));
    int*   rp_path = (int*)alloc((size_t)(NUM_NODES + 1) * sizeof(int));
    u16*   emb16   = (u16*)alloc((size_t)NUM_NODES * DIM * sizeof(u16));
    u16*   eA      = (u16*)alloc((size_t)NUM_NODES * DIM * sizeof(u16));
    u16*   eB      = (u16*)alloc((size_t)NUM_NODES * DIM * sizeof(u16));
    int*   m_col   = (int*)alloc((size_t)(E_pos + E_neg) * sizeof(int));
    float* m_val   = (float*)alloc((size_t)(E_pos + E_neg) * sizeof(float));
    float* sum_io  = (float*)d_out;  // running sum accumulates directly in d_out

    k_softmax_theta<<<1, 64, 0, stream>>>(theta, theta_w);
    k_expv<<<(E_path + 255) / 256, 256, 0, stream>>>(p_counts, theta_w, exp_v, E_path);

    int total_rp = 3 * (NUM_NODES + 1);
    k_row_ptr3<<<(total_rp + 255) / 256, 256, 0, stream>>>(
        pos_row, E_pos, rp_pos, neg_row, E_neg, rp_neg, p_row, E_path, rp_path);

    int cvt_threads = (NUM_NODES * DIM) / 4;
    k_cvt<<<(cvt_threads + 255) / 256, 256, 0, stream>>>(user_emb, item_emb, emb16);

    int merge_threads = E_pos + E_neg;
    k_merge<<<(merge_threads + 255) / 256, 256, 0, stream>>>(
        pos_row, pos_col, pos_val, E_pos,
        neg_row, neg_col, neg_val, E_neg,
        rp_pos, rp_neg, m_col, m_val);

    // one 8-lane group per row: 32 rows per 256-thread block
    int row_blocks = (NUM_NODES + 31) / 32;  // 3750

    k_path<<<row_blocks, 256, 0, stream>>>(emb16, exp_v, rp_path, p_col, eA, sum_io);
    k_layer<<<row_blocks, 256, 0, stream>>>(eA, eB, sum_io, rp_pos, rp_neg,
                                            m_col, m_val, 0);
    k_layer<<<row_blocks, 256, 0, stream>>>(eB, eA, sum_io, rp_pos, rp_neg,
                                            m_col, m_val, 0);
    k_layer<<<row_blocks, 256, 0, stream>>>(eA, eB, sum_io, rp_pos, rp_neg,
                                            m_col, m_val, 1);
}

// Round 8
// 461.650 us; speedup vs baseline: 1.3427x; 1.1286x over previous
//
#include <hip/hip_runtime.h>

#define NUM_USERS 80000
#define NUM_ITEMS 40000
#define NUM_NODES 120000
#define DIM 64
#define ALPHA_C 0.8f

typedef unsigned short u16;
typedef unsigned int u32;

// fp32 -> bf16 round-nearest-even
__device__ __forceinline__ u16 f2bf(float f) {
    union { float f; u32 i; } v;
    v.f = f;
    u32 i = v.i;
    u32 r = (i + 0x7FFFu + ((i >> 16) & 1u)) >> 16;
    return (u16)r;
}
__device__ __forceinline__ float lo_bf(u32 u) { return __uint_as_float(u << 16); }
__device__ __forceinline__ float hi_bf(u32 u) { return __uint_as_float(u & 0xffff0000u); }

// accumulate 8 bf16 (packed in uint4) * v into acc[8]
__device__ __forceinline__ void acc8(float* __restrict__ acc, float v, uint4 q) {
    const u32* p = (const u32*)&q;
#pragma unroll
    for (int k = 0; k < 4; ++k) {
        u32 u = p[k];
        acc[2 * k]     = fmaf(v, lo_bf(u), acc[2 * k]);
        acc[2 * k + 1] = fmaf(v, hi_bf(u), acc[2 * k + 1]);
    }
}

__device__ __forceinline__ uint4 ldrow(const u16* __restrict__ x, int c, int li) {
    return *((const uint4*)(x + (size_t)c * DIM) + li);
}

// ---------------------------------------------------------------------------
// Software-pipelined segment gather (8-lane group walks its whole segment).
// 2-stage prefetch of col/val + 1-stage prefetch of row gathers.
// Lane li (0..7) owns elements [8*li, 8*li+8) of the 64-dim row.
// Edge weights are multiplied by `scale` at use (folds pos/neg sign+alpha).
// If SUMV, also accumulates the UNSCALED sum of val into *vsum (every lane
// reads every val in the group-serial walk, so no reduction needed).
// ---------------------------------------------------------------------------
template <bool SUMV>
__device__ __forceinline__ void seg_pipe_t(const int* __restrict__ col,
                                           const float* __restrict__ val,
                                           int start, int end,
                                           const u16* __restrict__ x,
                                           int li, float scale,
                                           float* __restrict__ acc,
                                           float* __restrict__ vsum) {
    int n = end - start;
    const int* cp = col + start;
    const float* vp = val + start;
    float s = 0.f;
    int np = n >> 1;
    if (np >= 2) {
        float va0 = vp[0], va1 = vp[1];
        int   cb0 = cp[2], cb1 = cp[3];
        float vb0 = vp[2], vb1 = vp[3];
        uint4 xa0 = ldrow(x, cp[0], li);
        uint4 xa1 = ldrow(x, cp[1], li);
        for (int p = 2; p < np; ++p) {
            int   cc0 = cp[2 * p],     cc1 = cp[2 * p + 1];
            float vc0 = vp[2 * p],     vc1 = vp[2 * p + 1];
            uint4 xb0 = ldrow(x, cb0, li);
            uint4 xb1 = ldrow(x, cb1, li);
            acc8(acc, va0 * scale, xa0);
            acc8(acc, va1 * scale, xa1);
            if (SUMV) s += va0 + va1;
            va0 = vb0; va1 = vb1; xa0 = xb0; xa1 = xb1;
            cb0 = cc0; cb1 = cc1; vb0 = vc0; vb1 = vc1;
        }
        uint4 xb0 = ldrow(x, cb0, li);
        uint4 xb1 = ldrow(x, cb1, li);
        acc8(acc, va0 * scale, xa0);
        acc8(acc, va1 * scale, xa1);
        acc8(acc, vb0 * scale, xb0);
        acc8(acc, vb1 * scale, xb1);
        if (SUMV) s += va0 + va1 + vb0 + vb1;
        if (n & 1) {
            float v = vp[n - 1];
            uint4 xq = ldrow(x, cp[n - 1], li);
            acc8(acc, v * scale, xq);
            if (SUMV) s += v;
        }
    } else {
        for (int e = 0; e < n; ++e) {
            float v = vp[e];
            uint4 xq = ldrow(x, cp[e], li);
            acc8(acc, v * scale, xq);
            if (SUMV) s += v;
        }
    }
    if (SUMV) *vsum = s;
}

// ---------------------------------------------------------------------------
// K1: softmax over theta (6 elements) -> theta_w
// ---------------------------------------------------------------------------
__global__ void k_softmax_theta(const float* __restrict__ theta,
                                float* __restrict__ theta_w) {
    if (threadIdx.x == 0 && blockIdx.x == 0) {
        float m = -1e30f;
        for (int i = 0; i < 6; ++i) m = fmaxf(m, theta[i]);
        float e[6];
        float s = 0.f;
        for (int i = 0; i < 6; ++i) { e[i] = expf(theta[i] - m); s += e[i]; }
        for (int i = 0; i < 6; ++i) theta_w[i] = e[i] / s;
    }
}

// ---------------------------------------------------------------------------
// K2: exp_v[e] = exp(dot(p_counts[e,0:6], theta_w))   (no atomics)
// ---------------------------------------------------------------------------
__global__ void k_expv(const float* __restrict__ p_counts,
                       const float* __restrict__ theta_w,
                       float* __restrict__ exp_v, int E) {
    int i = blockIdx.x * blockDim.x + threadIdx.x;
    if (i >= E) return;
    const float* c = p_counts + (size_t)i * 6;
    float v = c[0] * theta_w[0] + c[1] * theta_w[1] + c[2] * theta_w[2] +
              c[3] * theta_w[3] + c[4] * theta_w[4] + c[5] * theta_w[5];
    exp_v[i] = expf(v);
}

// ---------------------------------------------------------------------------
// K3: all three CSR row_ptr arrays in one launch (rows sorted: np.unique)
// ---------------------------------------------------------------------------
__device__ __forceinline__ void lower_bound_ptr(const int* __restrict__ rows,
                                                int nnz, int r,
                                                int* __restrict__ ptr) {
    int lo = 0, hi = nnz;
    while (lo < hi) {
        int mid = (lo + hi) >> 1;
        if (rows[mid] < r) lo = mid + 1; else hi = mid;
    }
    ptr[r] = lo;
}

__global__ void k_row_ptr3(const int* __restrict__ rows_a, int nnz_a, int* __restrict__ pa,
                           const int* __restrict__ rows_b, int nnz_b, int* __restrict__ pb,
                           const int* __restrict__ rows_c, int nnz_c, int* __restrict__ pc) {
    int t = blockIdx.x * blockDim.x + threadIdx.x;
    int which = t / (NUM_NODES + 1);
    int r = t - which * (NUM_NODES + 1);
    if (which == 0) lower_bound_ptr(rows_a, nnz_a, r, pa);
    else if (which == 1) lower_bound_ptr(rows_b, nnz_b, r, pb);
    else if (which == 2) lower_bound_ptr(rows_c, nnz_c, r, pc);
}

// ---------------------------------------------------------------------------
// K4: convert user_emb || item_emb (fp32) -> bf16 table
// ---------------------------------------------------------------------------
__global__ void k_cvt(const float* __restrict__ user_emb,
                      const float* __restrict__ item_emb,
                      u16* __restrict__ emb16) {
    int i = blockIdx.x * blockDim.x + threadIdx.x;   // handles 4 floats
    size_t f = (size_t)i * 4;
    const size_t UTOT = (size_t)NUM_USERS * DIM;
    const size_t TOT = (size_t)NUM_NODES * DIM;
    if (f >= TOT) return;
    float4 v = (f < UTOT) ? *(const float4*)(user_emb + f)
                          : *(const float4*)(item_emb + (f - UTOT));
    ushort4 o;
    o.x = f2bf(v.x); o.y = f2bf(v.y); o.z = f2bf(v.z); o.w = f2bf(v.w);
    *(ushort4*)(emb16 + f) = o;
}

// ---------------------------------------------------------------------------
// K5: path SpMM with fused row-softmax. One 8-lane group per row.
//     acc = sum_e exp_v[e]*x[col[e]]; denominator accumulated in-walk;
//     e0 = acc / (sum + 1e-12)  (weights enter linearly). bf16 out only.
// ---------------------------------------------------------------------------
__global__ void k_path(const u16* __restrict__ emb16,
                       const float* __restrict__ exp_v,
                       const int* __restrict__ rp,
                       const int* __restrict__ cols,
                       u16* __restrict__ e0) {
    int t = blockIdx.x * blockDim.x + threadIdx.x;
    int row = t >> 3;            // one 8-lane group per row
    if (row >= NUM_NODES) return;
    int li = threadIdx.x & 7;
    int start = rp[row], end = rp[row + 1];

    float acc[8];
#pragma unroll
    for (int k = 0; k < 8; ++k) acc[k] = 0.f;
    float s = 0.f;

    seg_pipe_t<true>(cols, exp_v, start, end, emb16, li, 1.0f, acc, &s);

    float inv = 1.0f / (s + 1e-12f);
    u32 o[4];
#pragma unroll
    for (int k = 0; k < 4; ++k)
        o[k] = (u32)f2bf(acc[2 * k] * inv) | ((u32)f2bf(acc[2 * k + 1] * inv) << 16);
    *((uint4*)(e0 + (size_t)row * DIM) + li) = *(uint4*)o;
}

// ---------------------------------------------------------------------------
// K6: one propagation layer. One 8-lane group per row. Single accumulator:
//     acc = sum_pos val*x  - ALPHA * sum_neg val*x ; res = acc + ALPHA*e_in
//     FINAL=0: write res (bf16) to e_out.
//     FINAL=1: out = 0.25*(e0 + e1 + e_in + res)  (fp32, straight to d_out)
// ---------------------------------------------------------------------------
template <int FINAL>
__global__ void k_layer_t(const u16* __restrict__ e_in,
                          u16* __restrict__ e_out,
                          const u16* __restrict__ e0,
                          const u16* __restrict__ e1,
                          float* __restrict__ out,
                          const int* __restrict__ rp_p,
                          const int* __restrict__ col_p,
                          const float* __restrict__ val_p,
                          const int* __restrict__ rp_n,
                          const int* __restrict__ col_n,
                          const float* __restrict__ val_n) {
    int t = blockIdx.x * blockDim.x + threadIdx.x;
    int row = t >> 3;            // one 8-lane group per row
    if (row >= NUM_NODES) return;
    int li = threadIdx.x & 7;

    uint4 eq = *((const uint4*)(e_in + (size_t)row * DIM) + li);  // overlap with walk

    float acc[8];
#pragma unroll
    for (int k = 0; k < 8; ++k) acc[k] = 0.f;

    seg_pipe_t<false>(col_p, val_p, rp_p[row], rp_p[row + 1], e_in, li, 1.0f,
                      acc, nullptr);
    seg_pipe_t<false>(col_n, val_n, rp_n[row], rp_n[row + 1], e_in, li, -ALPHA_C,
                      acc, nullptr);

    const u32* ep = (const u32*)&eq;
    float res[8];
#pragma unroll
    for (int k = 0; k < 4; ++k) {
        res[2 * k]     = acc[2 * k]     + ALPHA_C * lo_bf(ep[k]);
        res[2 * k + 1] = acc[2 * k + 1] + ALPHA_C * hi_bf(ep[k]);
    }

    if (FINAL) {
        uint4 q0 = *((const uint4*)(e0 + (size_t)row * DIM) + li);
        uint4 q1 = *((const uint4*)(e1 + (size_t)row * DIM) + li);
        const u32* p0 = (const u32*)&q0;
        const u32* p1 = (const u32*)&q1;
        float4 o0, o1;
        float* oo[2] = { (float*)&o0, (float*)&o1 };
#pragma unroll
        for (int k = 0; k < 4; ++k) {
            float lo = res[2 * k]     + lo_bf(ep[k]) + lo_bf(p0[k]) + lo_bf(p1[k]);
            float hi = res[2 * k + 1] + hi_bf(ep[k]) + hi_bf(p0[k]) + hi_bf(p1[k]);
            oo[k >> 1][(k & 1) * 2]     = 0.25f * lo;
            oo[k >> 1][(k & 1) * 2 + 1] = 0.25f * hi;
        }
        float4* sp = (float4*)(out + (size_t)row * DIM) + li * 2;
        sp[0] = o0;
        sp[1] = o1;
    } else {
        u32 o[4];
#pragma unroll
        for (int k = 0; k < 4; ++k)
            o[k] = (u32)f2bf(res[2 * k]) | ((u32)f2bf(res[2 * k + 1]) << 16);
        *((uint4*)(e_out + (size_t)row * DIM) + li) = *(uint4*)o;
    }
}

// ---------------------------------------------------------------------------
extern "C" void kernel_launch(void* const* d_in, const int* in_sizes, int n_in,
                              void* d_out, int out_size, void* d_ws, size_t ws_size,
                              hipStream_t stream) {
    const float* user_emb = (const float*)d_in[0];
    const float* item_emb = (const float*)d_in[1];
    const float* theta    = (const float*)d_in[2];
    const int*   pos_row  = (const int*)d_in[3];
    const int*   pos_col  = (const int*)d_in[4];
    const float* pos_val  = (const float*)d_in[5];
    const int*   neg_row  = (const int*)d_in[6];
    const int*   neg_col  = (const int*)d_in[7];
    const float* neg_val  = (const float*)d_in[8];
    const int*   p_row    = (const int*)d_in[9];
    const int*   p_col    = (const int*)d_in[10];
    const float* p_counts = (const float*)d_in[11];
    const int E_pos  = in_sizes[3];
    const int E_neg  = in_sizes[6];
    const int E_path = in_sizes[9];

    // bump allocator over d_ws (256B aligned chunks)
    char* wsb = (char*)d_ws;
    size_t off = 0;
    auto alloc = [&](size_t bytes) -> void* {
        void* p = wsb + off;
        off = (off + bytes + 255) & ~(size_t)255;
        return p;
    };
    float* theta_w = (float*)alloc(6 * sizeof(float));
    float* exp_v   = (float*)alloc((size_t)E_path * sizeof(float));
    int*   rp_pos  = (int*)alloc((size_t)(NUM_NODES + 1) * sizeof(int));
    int*   rp_neg  = (int*)alloc((size_t)(NUM_NODES + 1) * sizeof(int));
    int*   rp_path = (int*)alloc((size_t)(NUM_NODES + 1) * sizeof(int));
    u16*   emb16   = (u16*)alloc((size_t)NUM_NODES * DIM * sizeof(u16));
    u16*   e0      = (u16*)alloc((size_t)NUM_NODES * DIM * sizeof(u16));
    u16*   e1      = (u16*)alloc((size_t)NUM_NODES * DIM * sizeof(u16));
    u16*   e2      = (u16*)alloc((size_t)NUM_NODES * DIM * sizeof(u16));
    float* outp    = (float*)d_out;

    k_softmax_theta<<<1, 64, 0, stream>>>(theta, theta_w);
    k_expv<<<(E_path + 255) / 256, 256, 0, stream>>>(p_counts, theta_w, exp_v, E_path);

    int total_rp = 3 * (NUM_NODES + 1);
    k_row_ptr3<<<(total_rp + 255) / 256, 256, 0, stream>>>(
        pos_row, E_pos, rp_pos, neg_row, E_neg, rp_neg, p_row, E_path, rp_path);

    int cvt_threads = (NUM_NODES * DIM) / 4;
    k_cvt<<<(cvt_threads + 255) / 256, 256, 0, stream>>>(user_emb, item_emb, emb16);

    // one 8-lane group per row: 32 rows per 256-thread block
    int row_blocks = (NUM_NODES + 31) / 32;  // 3750

    k_path<<<row_blocks, 256, 0, stream>>>(emb16, exp_v, rp_path, p_col, e0);
    k_layer_t<0><<<row_blocks, 256, 0, stream>>>(e0, e1, nullptr, nullptr, nullptr,
                                                 rp_pos, pos_col, pos_val,
                                                 rp_neg, neg_col, neg_val);
    k_layer_t<0><<<row_blocks, 256, 0, stream>>>(e1, e2, nullptr, nullptr, nullptr,
                                                 rp_pos, pos_col, pos_val,
                                                 rp_neg, neg_col, neg_val);
    k_layer_t<1><<<row_blocks, 256, 0, stream>>>(e2, nullptr, e0, e1, outp,
                                                 rp_pos, pos_col, pos_val,
                                                 rp_neg, neg_col, neg_val);
}